// Round 4
// baseline (140.472 us; speedup 1.0000x reference)
//
#include <hip/hip_runtime.h>

// Problem constants (match reference)
#define HWPX (512*512)      // pixels per batch
#define NB 2                // batches
#define NL 512              // EH*EW light directions
constexpr float PI_F = 3.14159265358979323846f;

// ws layout (bytes):
//   [0]      unsigned max-bits slot (f32 >= 0, bit-monotone)
//   [256]    float pack[2][512][8] : {hx, hy, hz, 0, e0*sp/60, e1*sp/60, e2*sp/60, 0}
//
// Key identity: (relu(s)/max)^64 == relu(s)^64 * (1/max)^64, and |s|<=1 for unit
// vectors, so we accumulate UNNORMALIZED sums while tracking the global max in
// the same pass, then scale the output by (1/max)^64 in a tiny finalize kernel.
// This deletes the entire separate max pass (~56 us).

__global__ void k_setup(const float* __restrict__ env,
                        float* __restrict__ pack,
                        unsigned* __restrict__ maxslot) {
    int m = threadIdx.x;            // 512 threads, one per light dir
    if (m == 0) *maxslot = 0u;      // re-zeroed every launch (replay-safe)
    int p = m >> 5;                 // phi index (EH=16)
    int t = m & 31;                 // theta index (EW=32)
    float phi = (float)p * (PI_F / 16.0f);
    float th  = (float)t * (2.0f * PI_F / 32.0f);
    float sp = sinf(phi), cp = cosf(phi);
    float st = sinf(th),  ct = cosf(th);
    // l = (st*sp, cp, -ct*sp); h = l + view(0,0,1), normalized
    float hx = st * sp;
    float hy = cp;
    float hz = 1.0f - ct * sp;
    float inv = rsqrtf(hx * hx + hy * hy + hz * hz);
    hx *= inv; hy *= inv; hz *= inv;
    float c = sp * (1.0f / 60.0f);  // solid-angle coeff and the /60 folded in
    #pragma unroll
    for (int b = 0; b < NB; ++b) {
        float* dst = pack + ((size_t)(b * NL + m)) * 8;
        const float* e = env + ((size_t)(b * NL + m)) * 3;
        dst[0] = hx; dst[1] = hy; dst[2] = hz; dst[3] = 0.0f;
        dst[4] = e[0] * c; dst[5] = e[1] * c; dst[6] = e[2] * c; dst[7] = 0.0f;
    }
}

__device__ __forceinline__ void load_normal(const float* __restrict__ normal, size_t pix,
                                            float& nx, float& ny, float& nz) {
    const float* p = normal + pix * 3;
    float c0 = p[0], c1 = p[1], c2 = p[2];
    // channel-reversed, [0,1] -> [-1,1], L2 normalize
    float x = (c2 - 0.5f) * 2.0f;
    float y = (c1 - 0.5f) * 2.0f;
    float z = (c0 - 0.5f) * 2.0f;
    float d2 = x * x + y * y + z * z;
    float inv = d2 > 0.0f ? rsqrtf(d2) : 0.0f;
    nx = x * inv; ny = y * inv; nz = z * inv;
}

// One pixel per thread: 2048 blocks -> 8 blocks/CU -> 32 waves/CU (full occupancy).
__global__ __launch_bounds__(256) void k_fused(const float* __restrict__ normal,
                                               const float* __restrict__ pack,
                                               float* __restrict__ out,
                                               unsigned* __restrict__ maxslot) {
    int bid = blockIdx.x;
    int b = bid >> 10;                              // 1024 blocks per batch
    int pix_in_b = (bid & 1023) * 256 + (int)threadIdx.x;

    float nx, ny, nz;
    load_normal(normal, (size_t)b * HWPX + pix_in_b, nx, ny, nz);

    const float* P = pack + (size_t)b * NL * 8;     // uniform per block -> s_loads
    float a0 = 0.0f, a1 = 0.0f, a2 = 0.0f, mx = 0.0f;

    #pragma unroll 8
    for (int m = 0; m < NL; ++m) {
        float4 h = *reinterpret_cast<const float4*>(P + (size_t)m * 8);
        float4 e = *reinterpret_cast<const float4*>(P + (size_t)m * 8 + 4);
        float s = fmaf(nx, h.x, fmaf(ny, h.y, nz * h.z));
        mx = fmaxf(mx, s);                          // track raw max (relu'd: mx>=0 seed)
        s = fmaxf(s, 0.0f);                         // relu
        float s2  = s * s;
        float s4  = s2 * s2;
        float s8  = s4 * s4;
        float s16 = s8 * s8;
        float s32 = s16 * s16;
        float s64 = s32 * s32;
        a0 = fmaf(s64, e.x, a0);
        a1 = fmaf(s64, e.y, a1);
        a2 = fmaf(s64, e.z, a2);
    }

    // wave-64 max reduce, one atomic per wave
    #pragma unroll
    for (int off = 32; off > 0; off >>= 1)
        mx = fmaxf(mx, __shfl_xor(mx, off));
    if ((threadIdx.x & 63) == 0)
        atomicMax(maxslot, __float_as_uint(mx));    // f32 >= 0: bit-monotone

    // unnormalized sums to out[b][c][h][w]; finalize scales by (1/max)^64
    float* ob = out + (size_t)b * 3 * HWPX;
    ob[0 * HWPX + pix_in_b] = a0;
    ob[1 * HWPX + pix_in_b] = a1;
    ob[2 * HWPX + pix_in_b] = a2;
}

__global__ __launch_bounds__(256) void k_finalize(float* __restrict__ out,
                                                  const unsigned* __restrict__ maxslot) {
    float im  = 1.0f / __uint_as_float(*maxslot);   // uniform scalar load
    float i2  = im * im;
    float i4  = i2 * i2;
    float i8  = i4 * i4;
    float i16 = i8 * i8;
    float i32 = i16 * i16;
    float scl = i32 * i32;                          // (1/max)^64
    int i = blockIdx.x * 256 + (int)threadIdx.x;    // over float4s
    float4* o = reinterpret_cast<float4*>(out);
    float4 v = o[i];
    v.x *= scl; v.y *= scl; v.z *= scl; v.w *= scl;
    o[i] = v;
}

extern "C" void kernel_launch(void* const* d_in, const int* in_sizes, int n_in,
                              void* d_out, int out_size, void* d_ws, size_t ws_size,
                              hipStream_t stream) {
    const float* env    = (const float*)d_in[0];   // (B,16,32,3) f32
    const float* normal = (const float*)d_in[1];   // (B,512,512,3) f32
    float* out = (float*)d_out;                    // (B,3,512,512) f32

    char* ws = (char*)d_ws;
    unsigned* maxslot = (unsigned*)ws;
    float* pack = (float*)(ws + 256);

    int nblocks = (NB * HWPX) / 256;               // 2048
    int fblocks = (NB * 3 * HWPX) / (4 * 256);     // 1536 (float4 granularity)

    hipLaunchKernelGGL(k_setup, dim3(1), dim3(NL), 0, stream, env, pack, maxslot);
    hipLaunchKernelGGL(k_fused, dim3(nblocks), dim3(256), 0, stream, normal, pack, out, maxslot);
    hipLaunchKernelGGL(k_finalize, dim3(fblocks), dim3(256), 0, stream, out, maxslot);
}

// Round 5
// 86.724 us; speedup vs baseline: 1.6198x; 1.6198x over previous
//
#include <hip/hip_runtime.h>

// Problem constants (match reference)
#define HWPX (512*512)      // pixels per batch
#define NB 2                // batches
#define NL 512              // EH*EW light directions
#define PXPT 2              // pixels per thread (amortize per-iteration overhead)
constexpr float PI_F = 3.14159265358979323846f;

// ws layout (bytes):
//   [0]      unsigned max-bits slot (f32 >= 0, bit-monotone)
//   [256]    float4 pack[2][512][2] : {hx,hy,hz,0} , {e0*sp/60, e1*sp/60, e2*sp/60, 0}
//
// Identity: (relu(s)/max)^64 == relu(s)^64 * (1/max)^64 with |s|<=1, so the
// shade pass accumulates UNNORMALIZED sums while tracking the global max;
// k_finalize scales by (1/max)^64. No separate max pass.
// The 16KB per-batch light table is staged in LDS so the unrolled inner loop
// is ds_read_b128 @ immediate offsets + pure VALU (no per-iter address math).

__global__ void k_setup(const float* __restrict__ env,
                        float4* __restrict__ pack,
                        unsigned* __restrict__ maxslot) {
    int m = threadIdx.x;            // 512 threads, one per light dir
    if (m == 0) *maxslot = 0u;      // re-zeroed every launch (replay-safe)
    int p = m >> 5;                 // phi index (EH=16)
    int t = m & 31;                 // theta index (EW=32)
    float phi = (float)p * (PI_F / 16.0f);
    float th  = (float)t * (2.0f * PI_F / 32.0f);
    float sp = sinf(phi), cp = cosf(phi);
    float st = sinf(th),  ct = cosf(th);
    // l = (st*sp, cp, -ct*sp); h = l + view(0,0,1), normalized
    float hx = st * sp;
    float hy = cp;
    float hz = 1.0f - ct * sp;
    float inv = rsqrtf(hx * hx + hy * hy + hz * hz);
    hx *= inv; hy *= inv; hz *= inv;
    float c = sp * (1.0f / 60.0f);  // solid-angle coeff and the /60 folded in
    #pragma unroll
    for (int b = 0; b < NB; ++b) {
        const float* e = env + ((size_t)(b * NL + m)) * 3;
        float4 hv; hv.x = hx; hv.y = hy; hv.z = hz; hv.w = 0.0f;
        float4 ev; ev.x = e[0] * c; ev.y = e[1] * c; ev.z = e[2] * c; ev.w = 0.0f;
        pack[(size_t)(b * NL + m) * 2 + 0] = hv;
        pack[(size_t)(b * NL + m) * 2 + 1] = ev;
    }
}

__device__ __forceinline__ void load_normal(const float* __restrict__ normal, size_t pix,
                                            float& nx, float& ny, float& nz) {
    const float* p = normal + pix * 3;
    float c0 = p[0], c1 = p[1], c2 = p[2];
    // channel-reversed, [0,1] -> [-1,1], L2 normalize
    float x = (c2 - 0.5f) * 2.0f;
    float y = (c1 - 0.5f) * 2.0f;
    float z = (c0 - 0.5f) * 2.0f;
    float d2 = x * x + y * y + z * z;
    float inv = d2 > 0.0f ? rsqrtf(d2) : 0.0f;
    nx = x * inv; ny = y * inv; nz = z * inv;
}

// PXPT=2, 256 threads -> 1024 blocks.
__global__ __launch_bounds__(256) void k_fused(const float* __restrict__ normal,
                                               const float4* __restrict__ pack,
                                               float* __restrict__ out,
                                               unsigned* __restrict__ maxslot) {
    __shared__ float4 sP[NL * 2];                  // 16 KB: this batch's light table
    __shared__ float swmax[4];                     // per-wave partial max

    int bid = blockIdx.x;
    int blocks_per_batch = HWPX / (256 * PXPT);    // 512
    int b = bid / blocks_per_batch;
    int base_in_b = (bid % blocks_per_batch) * (256 * PXPT) + (int)threadIdx.x;

    // stage light table: 1024 float4s, 4 per thread, coalesced
    {
        const float4* gp = pack + (size_t)b * NL * 2;
        int t = threadIdx.x;
        #pragma unroll
        for (int j = 0; j < 4; ++j)
            sP[t + j * 256] = gp[t + j * 256];
    }

    float nx[PXPT], ny[PXPT], nz[PXPT];
    #pragma unroll
    for (int k = 0; k < PXPT; ++k)
        load_normal(normal, (size_t)b * HWPX + base_in_b + k * 256, nx[k], ny[k], nz[k]);

    __syncthreads();

    float a0[PXPT], a1[PXPT], a2[PXPT];
    #pragma unroll
    for (int k = 0; k < PXPT; ++k) { a0[k] = 0.0f; a1[k] = 0.0f; a2[k] = 0.0f; }
    float mx = 0.0f;

    #pragma unroll 8
    for (int m = 0; m < NL; ++m) {
        float4 h = sP[m * 2 + 0];                  // ds_read_b128, immediate offset
        float4 e = sP[m * 2 + 1];
        #pragma unroll
        for (int k = 0; k < PXPT; ++k) {
            float s = fmaf(nx[k], h.x, fmaf(ny[k], h.y, nz[k] * h.z));
            mx = fmaxf(mx, s);                     // raw max (seed 0 == relu'd max)
            s = fmaxf(s, 0.0f);                    // relu
            float s2  = s * s;
            float s4  = s2 * s2;
            float s8  = s4 * s4;
            float s16 = s8 * s8;
            float s32 = s16 * s16;
            float s64 = s32 * s32;
            a0[k] = fmaf(s64, e.x, a0[k]);
            a1[k] = fmaf(s64, e.y, a1[k]);
            a2[k] = fmaf(s64, e.z, a2[k]);
        }
    }

    // wave-64 max reduce -> LDS -> one atomic per block
    #pragma unroll
    for (int off = 32; off > 0; off >>= 1)
        mx = fmaxf(mx, __shfl_xor(mx, off));
    int wid = threadIdx.x >> 6;
    if ((threadIdx.x & 63) == 0) swmax[wid] = mx;
    __syncthreads();
    if (threadIdx.x == 0) {
        float bm = fmaxf(fmaxf(swmax[0], swmax[1]), fmaxf(swmax[2], swmax[3]));
        atomicMax(maxslot, __float_as_uint(bm));   // f32 >= 0: bit-monotone
    }

    // unnormalized sums to out[b][c][h][w]; finalize scales by (1/max)^64
    float* ob = out + (size_t)b * 3 * HWPX;
    #pragma unroll
    for (int k = 0; k < PXPT; ++k) {
        int p = base_in_b + k * 256;
        ob[0 * HWPX + p] = a0[k];
        ob[1 * HWPX + p] = a1[k];
        ob[2 * HWPX + p] = a2[k];
    }
}

__global__ __launch_bounds__(256) void k_finalize(float* __restrict__ out,
                                                  const unsigned* __restrict__ maxslot) {
    float im  = 1.0f / __uint_as_float(*maxslot);   // uniform scalar load
    float i2  = im * im;
    float i4  = i2 * i2;
    float i8  = i4 * i4;
    float i16 = i8 * i8;
    float i32 = i16 * i16;
    float scl = i32 * i32;                          // (1/max)^64
    int i = blockIdx.x * 256 + (int)threadIdx.x;    // over float4s
    float4* o = reinterpret_cast<float4*>(out);
    float4 v = o[i];
    v.x *= scl; v.y *= scl; v.z *= scl; v.w *= scl;
    o[i] = v;
}

extern "C" void kernel_launch(void* const* d_in, const int* in_sizes, int n_in,
                              void* d_out, int out_size, void* d_ws, size_t ws_size,
                              hipStream_t stream) {
    const float* env    = (const float*)d_in[0];   // (B,16,32,3) f32
    const float* normal = (const float*)d_in[1];   // (B,512,512,3) f32
    float* out = (float*)d_out;                    // (B,3,512,512) f32

    char* ws = (char*)d_ws;
    unsigned* maxslot = (unsigned*)ws;
    float4* pack = (float4*)(ws + 256);

    int nblocks = (NB * HWPX) / (256 * PXPT);      // 1024
    int fblocks = (NB * 3 * HWPX) / (4 * 256);     // 1536 (float4 granularity)

    hipLaunchKernelGGL(k_setup, dim3(1), dim3(NL), 0, stream, env, pack, maxslot);
    hipLaunchKernelGGL(k_fused, dim3(nblocks), dim3(256), 0, stream, normal, pack, out, maxslot);
    hipLaunchKernelGGL(k_finalize, dim3(fblocks), dim3(256), 0, stream, out, maxslot);
}

// Round 6
// 84.037 us; speedup vs baseline: 1.6715x; 1.0320x over previous
//
#include <hip/hip_runtime.h>

// Problem constants (match reference)
#define HWPX (512*512)      // pixels per batch
#define NB 2                // batches
#define NL 512              // EH*EW light directions
#define PXPT 2              // pixel pair per thread -> packed-f32 lanes
constexpr float PI_F = 3.14159265358979323846f;

typedef float f2 __attribute__((ext_vector_type(2)));

// ws layout (bytes):
//   [0]      unsigned max-bits slot (f32 >= 0, bit-monotone)
//   [256]    float4 pack[2][512][3] : per light, PRE-DUPLICATED for packed math:
//            {hx,hx,hy,hy} {hz,hz,e0c,e0c} {e1c,e1c,e2c,e2c}  (c = sin(phi)/60)
//
// Identity: (relu(s)/max)^64 == relu(s)^64 * (1/max)^64 with |s|<=1, so the
// shade pass accumulates UNNORMALIZED sums while tracking the global max;
// k_finalize scales by (1/max)^64. No separate max pass.
// Light table staged in LDS; inner loop = 3x ds_read_b128 (broadcast) +
// 12 v_pk_* (packed f32, 2 pixels/instr) + 4 scalar v_max.

__global__ void k_setup(const float* __restrict__ env,
                        float4* __restrict__ pack,
                        unsigned* __restrict__ maxslot) {
    int m = threadIdx.x;            // 512 threads, one per light dir
    if (m == 0) *maxslot = 0u;      // re-zeroed every launch (replay-safe)
    int p = m >> 5;                 // phi index (EH=16)
    int t = m & 31;                 // theta index (EW=32)
    float phi = (float)p * (PI_F / 16.0f);
    float th  = (float)t * (2.0f * PI_F / 32.0f);
    float sp = sinf(phi), cp = cosf(phi);
    float st = sinf(th),  ct = cosf(th);
    // l = (st*sp, cp, -ct*sp); h = l + view(0,0,1), normalized
    float hx = st * sp;
    float hy = cp;
    float hz = 1.0f - ct * sp;
    float inv = rsqrtf(hx * hx + hy * hy + hz * hz);
    hx *= inv; hy *= inv; hz *= inv;
    float c = sp * (1.0f / 60.0f);  // solid-angle coeff and the /60 folded in
    #pragma unroll
    for (int b = 0; b < NB; ++b) {
        const float* e = env + ((size_t)(b * NL + m)) * 3;
        float e0 = e[0] * c, e1 = e[1] * c, e2 = e[2] * c;
        float4* dst = pack + (size_t)(b * NL + m) * 3;
        float4 q0; q0.x = hx; q0.y = hx; q0.z = hy; q0.w = hy;
        float4 q1; q1.x = hz; q1.y = hz; q1.z = e0; q1.w = e0;
        float4 q2; q2.x = e1; q2.y = e1; q2.z = e2; q2.w = e2;
        dst[0] = q0; dst[1] = q1; dst[2] = q2;
    }
}

__device__ __forceinline__ void load_normal(const float* __restrict__ normal, size_t pix,
                                            float& nx, float& ny, float& nz) {
    const float* p = normal + pix * 3;
    float c0 = p[0], c1 = p[1], c2 = p[2];
    // channel-reversed, [0,1] -> [-1,1], L2 normalize
    float x = (c2 - 0.5f) * 2.0f;
    float y = (c1 - 0.5f) * 2.0f;
    float z = (c0 - 0.5f) * 2.0f;
    float d2 = x * x + y * y + z * z;
    float inv = d2 > 0.0f ? rsqrtf(d2) : 0.0f;
    nx = x * inv; ny = y * inv; nz = z * inv;
}

// PXPT=2 packed, 256 threads -> 1024 blocks.
__global__ __launch_bounds__(256) void k_fused(const float* __restrict__ normal,
                                               const float4* __restrict__ pack,
                                               float* __restrict__ out,
                                               unsigned* __restrict__ maxslot) {
    __shared__ float4 sP[NL * 3];                  // 24 KB light table
    __shared__ float swmax[4];                     // per-wave partial max

    int bid = blockIdx.x;
    int blocks_per_batch = HWPX / (256 * PXPT);    // 512
    int b = bid / blocks_per_batch;
    int base_in_b = (bid % blocks_per_batch) * (256 * PXPT) + (int)threadIdx.x;

    // stage light table: 1536 float4s, 6 per thread, coalesced
    {
        const float4* gp = pack + (size_t)b * NL * 3;
        int t = threadIdx.x;
        #pragma unroll
        for (int j = 0; j < 6; ++j)
            sP[t + j * 256] = gp[t + j * 256];
    }

    float nxa, nya, nza, nxb, nyb, nzb;
    load_normal(normal, (size_t)b * HWPX + base_in_b,       nxa, nya, nza);
    load_normal(normal, (size_t)b * HWPX + base_in_b + 256, nxb, nyb, nzb);
    f2 nx2 = {nxa, nxb}, ny2 = {nya, nyb}, nz2 = {nza, nzb};

    __syncthreads();

    f2 a0 = {0.0f, 0.0f}, a1 = {0.0f, 0.0f}, a2 = {0.0f, 0.0f};
    float mx0 = 0.0f, mx1 = 0.0f;

    #pragma unroll 8
    for (int m = 0; m < NL; ++m) {
        float4 q0 = sP[m * 3 + 0];                 // {hx,hx,hy,hy}
        float4 q1 = sP[m * 3 + 1];                 // {hz,hz,e0,e0}
        float4 q2 = sP[m * 3 + 2];                 // {e1,e1,e2,e2}
        f2 hx2 = {q0.x, q0.y}, hy2 = {q0.z, q0.w};
        f2 hz2 = {q1.x, q1.y}, e02 = {q1.z, q1.w};
        f2 e12 = {q2.x, q2.y}, e22 = {q2.z, q2.w};

        f2 s = __builtin_elementwise_fma(nx2, hx2,
               __builtin_elementwise_fma(ny2, hy2, nz2 * hz2));   // 3x v_pk
        float sx = fmaxf(s.x, 0.0f);               // relu (scalar: no pk_max_f32)
        float sy = fmaxf(s.y, 0.0f);
        mx0 = fmaxf(mx0, sx);
        mx1 = fmaxf(mx1, sy);
        f2 r = {sx, sy};
        f2 r2  = r * r;                            // 6x v_pk_mul
        f2 r4  = r2 * r2;
        f2 r8  = r4 * r4;
        f2 r16 = r8 * r8;
        f2 r32 = r16 * r16;
        f2 r64 = r32 * r32;
        a0 = __builtin_elementwise_fma(r64, e02, a0);             // 3x v_pk_fma
        a1 = __builtin_elementwise_fma(r64, e12, a1);
        a2 = __builtin_elementwise_fma(r64, e22, a2);
    }

    // wave-64 max reduce -> LDS -> one atomic per block
    float mx = fmaxf(mx0, mx1);
    #pragma unroll
    for (int off = 32; off > 0; off >>= 1)
        mx = fmaxf(mx, __shfl_xor(mx, off));
    int wid = threadIdx.x >> 6;
    if ((threadIdx.x & 63) == 0) swmax[wid] = mx;
    __syncthreads();
    if (threadIdx.x == 0) {
        float bm = fmaxf(fmaxf(swmax[0], swmax[1]), fmaxf(swmax[2], swmax[3]));
        atomicMax(maxslot, __float_as_uint(bm));   // f32 >= 0: bit-monotone
    }

    // unnormalized sums to out[b][c][h][w]; finalize scales by (1/max)^64
    float* ob = out + (size_t)b * 3 * HWPX;
    #pragma unroll
    for (int k = 0; k < PXPT; ++k) {
        int p = base_in_b + k * 256;
        ob[0 * HWPX + p] = a0[k];
        ob[1 * HWPX + p] = a1[k];
        ob[2 * HWPX + p] = a2[k];
    }
}

__global__ __launch_bounds__(256) void k_finalize(float* __restrict__ out,
                                                  const unsigned* __restrict__ maxslot) {
    float im  = 1.0f / __uint_as_float(*maxslot);   // uniform scalar load
    float i2  = im * im;
    float i4  = i2 * i2;
    float i8  = i4 * i4;
    float i16 = i8 * i8;
    float i32 = i16 * i16;
    float scl = i32 * i32;                          // (1/max)^64
    int i = blockIdx.x * 256 + (int)threadIdx.x;    // over float4s
    float4* o = reinterpret_cast<float4*>(out);
    float4 v = o[i];
    v.x *= scl; v.y *= scl; v.z *= scl; v.w *= scl;
    o[i] = v;
}

extern "C" void kernel_launch(void* const* d_in, const int* in_sizes, int n_in,
                              void* d_out, int out_size, void* d_ws, size_t ws_size,
                              hipStream_t stream) {
    const float* env    = (const float*)d_in[0];   // (B,16,32,3) f32
    const float* normal = (const float*)d_in[1];   // (B,512,512,3) f32
    float* out = (float*)d_out;                    // (B,3,512,512) f32

    char* ws = (char*)d_ws;
    unsigned* maxslot = (unsigned*)ws;
    float4* pack = (float4*)(ws + 256);

    int nblocks = (NB * HWPX) / (256 * PXPT);      // 1024
    int fblocks = (NB * 3 * HWPX) / (4 * 256);     // 1536 (float4 granularity)

    hipLaunchKernelGGL(k_setup, dim3(1), dim3(NL), 0, stream, env, pack, maxslot);
    hipLaunchKernelGGL(k_fused, dim3(nblocks), dim3(256), 0, stream, normal, pack, out, maxslot);
    hipLaunchKernelGGL(k_finalize, dim3(fblocks), dim3(256), 0, stream, out, maxslot);
}

// Round 7
// 79.785 us; speedup vs baseline: 1.7606x; 1.0533x over previous
//
#include <hip/hip_runtime.h>

// Problem constants (match reference)
#define HWPX (512*512)      // pixels per batch
#define NB 2                // batches
#define NL 512              // EH*EW light directions
#define PXPT 4              // 4 pixels (2 packed pairs) per thread
constexpr float PI_F = 3.14159265358979323846f;

typedef float f2 __attribute__((ext_vector_type(2)));

// ws layout (bytes):
//   [0]      unsigned max-bits slot (f32 >= 0, bit-monotone)
//   [256]    float2 tab[2][512][3] : COMPACT per light: {hx,hy} {hz,e0c} {e1c,e2c}
//            (c = sin(phi)/60 folded into env)
//
// Identity: (relu(s)/max)^64 == relu(s)^64 * (1/max)^64 with |s|<=1 -> accumulate
// UNNORMALIZED, track global max in-pass, k_finalize scales by (1/max)^64.
//
// R5 lesson: broadcast ds_read still pays full 64-lane data-return bandwidth
// (16B/lane), so LDS traffic = bytes/lane * iters is the binding pipe. This
// version halves bytes/light (24B compact) and doubles pixels served per read
// (PXPT=4): DS ~20us, VALU 26-48us -> VALU-bound.

__global__ void k_setup(const float* __restrict__ env,
                        float2* __restrict__ tab,
                        unsigned* __restrict__ maxslot) {
    int m = threadIdx.x;            // 512 threads, one per light dir
    if (m == 0) *maxslot = 0u;      // re-zeroed every launch (replay-safe)
    int p = m >> 5;                 // phi index (EH=16)
    int t = m & 31;                 // theta index (EW=32)
    float phi = (float)p * (PI_F / 16.0f);
    float th  = (float)t * (2.0f * PI_F / 32.0f);
    float sp = sinf(phi), cp = cosf(phi);
    float st = sinf(th),  ct = cosf(th);
    // l = (st*sp, cp, -ct*sp); h = l + view(0,0,1), normalized
    float hx = st * sp;
    float hy = cp;
    float hz = 1.0f - ct * sp;
    float inv = rsqrtf(hx * hx + hy * hy + hz * hz);
    hx *= inv; hy *= inv; hz *= inv;
    float c = sp * (1.0f / 60.0f);  // solid-angle coeff and the /60 folded in
    #pragma unroll
    for (int b = 0; b < NB; ++b) {
        const float* e = env + ((size_t)(b * NL + m)) * 3;
        float2* dst = tab + (size_t)(b * NL + m) * 3;
        float2 q0; q0.x = hx;       q0.y = hy;
        float2 q1; q1.x = hz;       q1.y = e[0] * c;
        float2 q2; q2.x = e[1] * c; q2.y = e[2] * c;
        dst[0] = q0; dst[1] = q1; dst[2] = q2;
    }
}

__device__ __forceinline__ void load_normal(const float* __restrict__ normal, size_t pix,
                                            float& nx, float& ny, float& nz) {
    const float* p = normal + pix * 3;
    float c0 = p[0], c1 = p[1], c2 = p[2];
    // channel-reversed, [0,1] -> [-1,1], L2 normalize
    float x = (c2 - 0.5f) * 2.0f;
    float y = (c1 - 0.5f) * 2.0f;
    float z = (c0 - 0.5f) * 2.0f;
    float d2 = x * x + y * y + z * z;
    float inv = d2 > 0.0f ? rsqrtf(d2) : 0.0f;
    nx = x * inv; ny = y * inv; nz = z * inv;
}

// PXPT=4 (2 packed pairs), 256 threads -> 512 blocks (2 blocks/CU, 8 waves/CU).
__global__ __launch_bounds__(256) void k_fused(const float* __restrict__ normal,
                                               const float2* __restrict__ tab,
                                               float* __restrict__ out,
                                               unsigned* __restrict__ maxslot) {
    __shared__ float2 sT[NL * 3];                  // 12 KB compact light table
    __shared__ float swmax[4];                     // per-wave partial max

    int bid = blockIdx.x;
    int blocks_per_batch = HWPX / (256 * PXPT);    // 256
    int b = bid / blocks_per_batch;
    int base_in_b = (bid % blocks_per_batch) * (256 * PXPT) + (int)threadIdx.x;

    // stage light table: 768 float4s, 3 per thread, coalesced
    {
        const float4* gp = reinterpret_cast<const float4*>(tab + (size_t)b * NL * 3);
        float4* sp4 = reinterpret_cast<float4*>(sT);
        int t = threadIdx.x;
        #pragma unroll
        for (int j = 0; j < 3; ++j)
            sp4[t + j * 256] = gp[t + j * 256];
    }

    // load 4 normals -> 2 packed pairs
    float nxs[PXPT], nys[PXPT], nzs[PXPT];
    #pragma unroll
    for (int k = 0; k < PXPT; ++k)
        load_normal(normal, (size_t)b * HWPX + base_in_b + k * 256,
                    nxs[k], nys[k], nzs[k]);
    f2 nx2[2], ny2[2], nz2[2];
    #pragma unroll
    for (int k = 0; k < 2; ++k) {
        nx2[k] = f2{nxs[2*k], nxs[2*k+1]};
        ny2[k] = f2{nys[2*k], nys[2*k+1]};
        nz2[k] = f2{nzs[2*k], nzs[2*k+1]};
    }

    __syncthreads();

    f2 a0[2], a1[2], a2[2];
    #pragma unroll
    for (int k = 0; k < 2; ++k) { a0[k] = f2{0,0}; a1[k] = f2{0,0}; a2[k] = f2{0,0}; }
    float mx = 0.0f;

    #pragma unroll 8
    for (int m = 0; m < NL; ++m) {
        float2 q0 = sT[m * 3 + 0];                 // {hx,hy}
        float2 q1 = sT[m * 3 + 1];                 // {hz,e0}
        float2 q2 = sT[m * 3 + 2];                 // {e1,e2}
        f2 hx2 = {q0.x, q0.x}, hy2 = {q0.y, q0.y}, hz2 = {q1.x, q1.x};
        f2 e02 = {q1.y, q1.y}, e12 = {q2.x, q2.x}, e22 = {q2.y, q2.y};

        #pragma unroll
        for (int k = 0; k < 2; ++k) {
            f2 s = __builtin_elementwise_fma(nx2[k], hx2,
                   __builtin_elementwise_fma(ny2[k], hy2, nz2[k] * hz2));
            float sx = fmaxf(s.x, 0.0f);           // relu (no v_pk_max_f32)
            float sy = fmaxf(s.y, 0.0f);
            mx = fmaxf(mx, fmaxf(sx, sy));         // -> v_max3_f32
            f2 r = {sx, sy};
            f2 r2  = r * r;
            f2 r4  = r2 * r2;
            f2 r8  = r4 * r4;
            f2 r16 = r8 * r8;
            f2 r32 = r16 * r16;
            f2 r64 = r32 * r32;
            a0[k] = __builtin_elementwise_fma(r64, e02, a0[k]);
            a1[k] = __builtin_elementwise_fma(r64, e12, a1[k]);
            a2[k] = __builtin_elementwise_fma(r64, e22, a2[k]);
        }
    }

    // wave-64 max reduce -> LDS -> one atomic per block
    #pragma unroll
    for (int off = 32; off > 0; off >>= 1)
        mx = fmaxf(mx, __shfl_xor(mx, off));
    int wid = threadIdx.x >> 6;
    if ((threadIdx.x & 63) == 0) swmax[wid] = mx;
    __syncthreads();
    if (threadIdx.x == 0) {
        float bm = fmaxf(fmaxf(swmax[0], swmax[1]), fmaxf(swmax[2], swmax[3]));
        atomicMax(maxslot, __float_as_uint(bm));   // f32 >= 0: bit-monotone
    }

    // unnormalized sums to out[b][c][h][w]; finalize scales by (1/max)^64
    float* ob = out + (size_t)b * 3 * HWPX;
    #pragma unroll
    for (int k = 0; k < PXPT; ++k) {
        int p = base_in_b + k * 256;
        f2 v0 = a0[k >> 1], v1 = a1[k >> 1], v2 = a2[k >> 1];
        int h = k & 1;
        ob[0 * HWPX + p] = v0[h];
        ob[1 * HWPX + p] = v1[h];
        ob[2 * HWPX + p] = v2[h];
    }
}

__global__ __launch_bounds__(256) void k_finalize(float* __restrict__ out,
                                                  const unsigned* __restrict__ maxslot) {
    float im  = 1.0f / __uint_as_float(*maxslot);   // uniform scalar load
    float i2  = im * im;
    float i4  = i2 * i2;
    float i8  = i4 * i4;
    float i16 = i8 * i8;
    float i32 = i16 * i16;
    float scl = i32 * i32;                          // (1/max)^64
    int i = blockIdx.x * 256 + (int)threadIdx.x;    // over float4s
    float4* o = reinterpret_cast<float4*>(out);
    float4 v = o[i];
    v.x *= scl; v.y *= scl; v.z *= scl; v.w *= scl;
    o[i] = v;
}

extern "C" void kernel_launch(void* const* d_in, const int* in_sizes, int n_in,
                              void* d_out, int out_size, void* d_ws, size_t ws_size,
                              hipStream_t stream) {
    const float* env    = (const float*)d_in[0];   // (B,16,32,3) f32
    const float* normal = (const float*)d_in[1];   // (B,512,512,3) f32
    float* out = (float*)d_out;                    // (B,3,512,512) f32

    char* ws = (char*)d_ws;
    unsigned* maxslot = (unsigned*)ws;
    float2* tab = (float2*)(ws + 256);

    int nblocks = (NB * HWPX) / (256 * PXPT);      // 512
    int fblocks = (NB * 3 * HWPX) / (4 * 256);     // 1536 (float4 granularity)

    hipLaunchKernelGGL(k_setup, dim3(1), dim3(NL), 0, stream, env, tab, maxslot);
    hipLaunchKernelGGL(k_fused, dim3(nblocks), dim3(256), 0, stream, normal, tab, out, maxslot);
    hipLaunchKernelGGL(k_finalize, dim3(fblocks), dim3(256), 0, stream, out, maxslot);
}